// Round 1
// baseline (38627.036 us; speedup 1.0000x reference)
//
#include <hip/hip_runtime.h>
#include <math.h>

#define S 256
#define H 1024
#define SH (S*H)

__device__ __forceinline__ float sigm(float x) { return 1.0f / (1.0f + expf(-x)); }

// ---------------------------------------------------------------------------
// Transpose W (H x H, row-major [j][k]) -> Wt [k][j] so GEMM weight loads are
// lane-coalesced along j.
// ---------------------------------------------------------------------------
__global__ __launch_bounds__(256) void k_transpose(const float* __restrict__ Wsrc,
                                                   float* __restrict__ Wt) {
    __shared__ float tile[32][33];
    int bx = blockIdx.x & 31;        // j-block
    int by = blockIdx.x >> 5;        // k-block
    int tx = threadIdx.x & 31;
    int ty = threadIdx.x >> 5;       // 0..7
    int j0 = bx * 32, k0 = by * 32;
#pragma unroll
    for (int i = 0; i < 32; i += 8)
        tile[ty + i][tx] = Wsrc[(j0 + ty + i) * H + (k0 + tx)];
    __syncthreads();
#pragma unroll
    for (int i = 0; i < 32; i += 8)
        Wt[(k0 + ty + i) * H + (j0 + tx)] = tile[tx][ty + i];
}

// ---------------------------------------------------------------------------
// Prologue: A1 = X (hf starts at 0), hfn = hbn = 0.
// ---------------------------------------------------------------------------
__global__ __launch_bounds__(256) void k_init(const float* __restrict__ X,
                                              float* __restrict__ A1,
                                              float* __restrict__ hfn,
                                              float* __restrict__ hbn) {
    int idx = blockIdx.x * 256 + threadIdx.x;   // grid 1024 -> SH threads
    A1[idx] = X[idx];
    hfn[idx] = 0.0f;
    hbn[idx] = 0.0f;
}

// ---------------------------------------------------------------------------
// GEMM core: one wave computes rows s0..s0+3 x 64 cols (col = lane).
// arow points at A + s0*H ; wtj points at Wt + j (column j, stride H).
// A-row loads are wave-uniform (HW broadcast); wt loads are lane-coalesced.
// ---------------------------------------------------------------------------
__device__ __forceinline__ void gemm4x64(const float* __restrict__ arow,
                                         const float* __restrict__ wtj,
                                         float acc[4]) {
    const float* a0 = arow;
    const float* a1 = arow + H;
    const float* a2 = arow + 2 * H;
    const float* a3 = arow + 3 * H;
    float s0 = 0.f, s1 = 0.f, s2 = 0.f, s3 = 0.f;
#pragma unroll 4
    for (int k = 0; k < H; k += 4) {
        float4 q0 = *(const float4*)(a0 + k);
        float4 q1 = *(const float4*)(a1 + k);
        float4 q2 = *(const float4*)(a2 + k);
        float4 q3 = *(const float4*)(a3 + k);
        float w0 = wtj[(k + 0) * H];
        float w1 = wtj[(k + 1) * H];
        float w2 = wtj[(k + 2) * H];
        float w3 = wtj[(k + 3) * H];
        s0 = fmaf(q0.x, w0, s0); s0 = fmaf(q0.y, w1, s0); s0 = fmaf(q0.z, w2, s0); s0 = fmaf(q0.w, w3, s0);
        s1 = fmaf(q1.x, w0, s1); s1 = fmaf(q1.y, w1, s1); s1 = fmaf(q1.z, w2, s1); s1 = fmaf(q1.w, w3, s1);
        s2 = fmaf(q2.x, w0, s2); s2 = fmaf(q2.y, w1, s2); s2 = fmaf(q2.z, w2, s2); s2 = fmaf(q2.w, w3, s2);
        s3 = fmaf(q3.x, w0, s3); s3 = fmaf(q3.y, w1, s3); s3 = fmaf(q3.z, w2, s3); s3 = fmaf(q3.w, w3, s3);
    }
    acc[0] = s0; acc[1] = s1; acc[2] = s2; acc[3] = s3;
}

__device__ __forceinline__ int xcd_swizzle(unsigned gbx) {
    // bijective for 256 blocks: give each XCD contiguous logical-block chunks
    return (int)((gbx & 7u) * 32u + (gbx >> 3));
}

// ---------------------------------------------------------------------------
// K1: x1 = sigmoid((X+hfn) @ W1^T + b1)  with A1 = X+hfn prematerialized.
// Epilogue writes A2 = hbn + x1 and A3 = x1 + hfn. Also zeroes this step's
// stats buffer (before K2 accumulates into it).
// ---------------------------------------------------------------------------
__global__ __launch_bounds__(256) void k_gemm1(
    const float* __restrict__ A1, const float* __restrict__ wt1,
    const float* __restrict__ b1v,
    const float* __restrict__ hfn, const float* __restrict__ hbn,
    float* __restrict__ A2, float* __restrict__ A3,
    float* __restrict__ statz) {
    if (blockIdx.x < 16)
        statz[blockIdx.x * 256 + threadIdx.x] = 0.0f;   // 4*H floats total

    int g = xcd_swizzle(blockIdx.x);
    int sb = g & 15, jb = g >> 4;
    int lane = threadIdx.x & 63, w = threadIdx.x >> 6;
    int j = (jb << 6) + lane;
    int s0 = (sb << 4) + (w << 2);

    float acc[4];
    gemm4x64(A1 + s0 * H, wt1 + j, acc);
    float bias = b1v[j];
#pragma unroll
    for (int r = 0; r < 4; ++r) {
        float x1v = sigm(acc[r] + bias);
        int o = (s0 + r) * H + j;
        A2[o] = hbn[o] + x1v;
        A3[o] = x1v + hfn[o];
    }
}

// ---------------------------------------------------------------------------
// K2: hb2 = sigmoid(A2 @ W2^T + b2) -> rawB ; hf2 = sigmoid(A3 @ W3^T + b3)
// -> rawF ; per-column {sum, sumsq} accumulated into stats via atomics.
// On the final step also writes out = 0.5*(hf2 + hb2).
// ---------------------------------------------------------------------------
__global__ __launch_bounds__(256) void k_gemm23(
    const float* __restrict__ A2, const float* __restrict__ A3,
    const float* __restrict__ wt2, const float* __restrict__ wt3,
    const float* __restrict__ b2v, const float* __restrict__ b3v,
    float* __restrict__ rawF, float* __restrict__ rawB,
    float* __restrict__ stats, float* __restrict__ outp, int writeOut) {
    __shared__ float red[4][64][2];

    int g = xcd_swizzle(blockIdx.x);
    int sb = g & 15, jb = g >> 4;
    int lane = threadIdx.x & 63, w = threadIdx.x >> 6;
    int j = (jb << 6) + lane;
    int s0 = (sb << 4) + (w << 2);

    float acc[4];
    float vb[4];

    // ---- mm2: hb2 ----
    gemm4x64(A2 + s0 * H, wt2 + j, acc);
    {
        float bias = b2v[j];
        float sum = 0.f, ssq = 0.f;
#pragma unroll
        for (int r = 0; r < 4; ++r) {
            float v = sigm(acc[r] + bias);
            vb[r] = v;
            rawB[(s0 + r) * H + j] = v;
            sum += v; ssq += v * v;
        }
        red[w][lane][0] = sum; red[w][lane][1] = ssq;
    }
    __syncthreads();
    if (w == 0) {
        float ts = red[0][lane][0] + red[1][lane][0] + red[2][lane][0] + red[3][lane][0];
        float tq = red[0][lane][1] + red[1][lane][1] + red[2][lane][1] + red[3][lane][1];
        atomicAdd(&stats[2 * H + j], ts);
        atomicAdd(&stats[3 * H + j], tq);
    }
    __syncthreads();

    // ---- mm3: hf2 ----
    gemm4x64(A3 + s0 * H, wt3 + j, acc);
    {
        float bias = b3v[j];
        float sum = 0.f, ssq = 0.f;
#pragma unroll
        for (int r = 0; r < 4; ++r) {
            float v = sigm(acc[r] + bias);
            rawF[(s0 + r) * H + j] = v;
            if (writeOut)
                outp[(s0 + r) * H + j] = 0.5f * (v + vb[r]);
            sum += v; ssq += v * v;
        }
        red[w][lane][0] = sum; red[w][lane][1] = ssq;
    }
    __syncthreads();
    if (w == 0) {
        float ts = red[0][lane][0] + red[1][lane][0] + red[2][lane][0] + red[3][lane][0];
        float tq = red[0][lane][1] + red[1][lane][1] + red[2][lane][1] + red[3][lane][1];
        atomicAdd(&stats[0 * H + j], ts);
        atomicAdd(&stats[1 * H + j], tq);
    }
}

// ---------------------------------------------------------------------------
// K3: BatchNorm both raws (training-mode, biased var, eps=1e-5), write
// hfn/hbn, and prematerialize A1 = X + hfn for the next step's GEMM1.
// ---------------------------------------------------------------------------
__global__ __launch_bounds__(256) void k_norm(
    const float* __restrict__ rawF, const float* __restrict__ rawB,
    const float* __restrict__ stats, const float* __restrict__ X,
    const float* __restrict__ gF, const float* __restrict__ bF,
    const float* __restrict__ gB, const float* __restrict__ bB,
    float* __restrict__ hfn, float* __restrict__ hbn, float* __restrict__ A1) {
    int t = blockIdx.x * 256 + threadIdx.x;   // grid 256 -> 65536 threads
    int idx = t * 4;
    int k = idx & (H - 1);
    const float inv = 1.0f / (float)S;

    float4 sF = *(const float4*)(stats + k);
    float4 qF = *(const float4*)(stats + H + k);
    float4 sB = *(const float4*)(stats + 2 * H + k);
    float4 qB = *(const float4*)(stats + 3 * H + k);
    float4 gF4 = *(const float4*)(gF + k);
    float4 bF4 = *(const float4*)(bF + k);
    float4 gB4 = *(const float4*)(gB + k);
    float4 bB4 = *(const float4*)(bB + k);
    float4 rf = *(const float4*)(rawF + idx);
    float4 rb = *(const float4*)(rawB + idx);
    float4 xv = *(const float4*)(X + idx);

    float4 ho, bo, ao;
#define COMPONENT(c)                                                        \
    {                                                                       \
        float mF = sF.c * inv;                                              \
        float vF = qF.c * inv - mF * mF;                                    \
        float scF = rsqrtf(vF + 1e-5f) * gF4.c;                             \
        float hv = fmaf(rf.c - mF, scF, bF4.c);                             \
        float mB = sB.c * inv;                                              \
        float vB = qB.c * inv - mB * mB;                                    \
        float scB = rsqrtf(vB + 1e-5f) * gB4.c;                             \
        float hbv = fmaf(rb.c - mB, scB, bB4.c);                            \
        ho.c = hv; bo.c = hbv; ao.c = xv.c + hv;                            \
    }
    COMPONENT(x) COMPONENT(y) COMPONENT(z) COMPONENT(w)
#undef COMPONENT

    *(float4*)(hfn + idx) = ho;
    *(float4*)(hbn + idx) = bo;
    *(float4*)(A1 + idx) = ao;
}

// ---------------------------------------------------------------------------
// Host: 770 launches captured into one graph.
//   Dead in the reference (verified by dataflow): fc/bc LSTM cells (only enter
//   the discarded carry), W4/b4 (interaction's x0 return is dropped), all
//   outs except the last step. Only the hf/hb BN-chain must run 256x.
// ---------------------------------------------------------------------------
extern "C" void kernel_launch(void* const* d_in, const int* in_sizes, int n_in,
                              void* d_out, int out_size, void* d_ws, size_t ws_size,
                              hipStream_t stream) {
    (void)in_sizes; (void)n_in; (void)out_size; (void)ws_size;

    const float* X  = (const float*)d_in[0];
    const float* W1 = (const float*)d_in[1];
    const float* b1 = (const float*)d_in[2];
    const float* W2 = (const float*)d_in[3];
    const float* b2 = (const float*)d_in[4];
    const float* W3 = (const float*)d_in[5];
    const float* b3 = (const float*)d_in[6];
    const float* gf = (const float*)d_in[17];
    const float* bf = (const float*)d_in[18];
    const float* gb = (const float*)d_in[19];
    const float* bb = (const float*)d_in[20];

    float* ws   = (float*)d_ws;
    float* wt1  = ws;                 // H*H
    float* wt2  = wt1 + H * H;
    float* wt3  = wt2 + H * H;
    float* A1   = wt3 + H * H;        // S*H each from here
    float* A2   = A1 + SH;
    float* A3   = A2 + SH;
    float* hfn  = A3 + SH;
    float* hbn  = hfn + SH;
    float* rawf = hbn + SH;           // 2 * S*H (parity)
    float* rawb = rawf + 2 * SH;
    float* stats = rawb + 2 * SH;     // 2 * 4*H (parity x {sumF,ssqF,sumB,ssqB})

    k_transpose<<<1024, 256, 0, stream>>>(W1, wt1);
    k_transpose<<<1024, 256, 0, stream>>>(W2, wt2);
    k_transpose<<<1024, 256, 0, stream>>>(W3, wt3);
    k_init<<<1024, 256, 0, stream>>>(X, A1, hfn, hbn);

    for (int s = 0; s < S; ++s) {
        int par = (s + 1) & 1;
        float* st = stats + par * 4 * H;
        k_gemm1<<<256, 256, 0, stream>>>(A1, wt1, b1, hfn, hbn, A2, A3, st);
        k_gemm23<<<256, 256, 0, stream>>>(A2, A3, wt2, wt3, b2, b3,
                                          rawf + par * SH, rawb + par * SH, st,
                                          (float*)d_out, (s == S - 1) ? 1 : 0);
        if (s < S - 1)
            k_norm<<<256, 256, 0, stream>>>(rawf + par * SH, rawb + par * SH, st, X,
                                            gf, bf, gb, bb, hfn, hbn, A1);
    }
}

// Round 2
// 23279.137 us; speedup vs baseline: 1.6593x; 1.6593x over previous
//
#include <hip/hip_runtime.h>
#include <math.h>

#define S 256
#define H 1024
#define SH (S*H)
#define EPS 1e-5f

__device__ __forceinline__ float sigm(float x) { return 1.0f / (1.0f + expf(-x)); }

// bijective for 256 blocks: XCD x gets 32 contiguous logical blocks -> its
// 2 weight col-slabs (2 x 256KB x 3 mats = 1.5MB) stay L2-resident all steps
__device__ __forceinline__ int xcd_swizzle(unsigned gbx) {
    return (int)((gbx & 7u) * 32u + (gbx >> 3));
}

// ---------------------------------------------------------------------------
// Transpose W (H x H, row-major [j][k]) -> Wt [k][j]: GEMM weight loads
// become lane-coalesced along j (256B per wave64 instruction).
// ---------------------------------------------------------------------------
__global__ __launch_bounds__(256) void k_transpose(const float* __restrict__ Wsrc,
                                                   float* __restrict__ Wt) {
    __shared__ float tile[32][33];
    int bx = blockIdx.x & 31;
    int by = blockIdx.x >> 5;
    int tx = threadIdx.x & 31;
    int ty = threadIdx.x >> 5;
    int j0 = bx * 32, k0 = by * 32;
#pragma unroll
    for (int i = 0; i < 32; i += 8)
        tile[ty + i][tx] = Wsrc[(j0 + ty + i) * H + (k0 + tx)];
    __syncthreads();
#pragma unroll
    for (int i = 0; i < 32; i += 8)
        Wt[(k0 + ty + i) * H + (j0 + tx)] = tile[tx][ty + i];
}

// ---------------------------------------------------------------------------
// GEMM half-K compute: wave's 2 rows (uniform ds_read_b128 broadcast) x 64
// cols (lane). W column loads are lane-coalesced, latency hidden by unroll.
// ---------------------------------------------------------------------------
__device__ __forceinline__ void gemm2x64_half(const float* __restrict__ a0,
                                              const float* __restrict__ wk,
                                              float& acc0, float& acc1) {
    const float* a1 = a0 + 512;
    float s0 = acc0, s1 = acc1;
#pragma unroll 8
    for (int k = 0; k < 512; k += 4) {
        float4 q0 = *(const float4*)(a0 + k);
        float4 q1 = *(const float4*)(a1 + k);
        float w0 = wk[(k + 0) * H];
        float w1 = wk[(k + 1) * H];
        float w2 = wk[(k + 2) * H];
        float w3 = wk[(k + 3) * H];
        s0 = fmaf(q0.x, w0, s0); s0 = fmaf(q0.y, w1, s0);
        s0 = fmaf(q0.z, w2, s0); s0 = fmaf(q0.w, w3, s0);
        s1 = fmaf(q1.x, w0, s1); s1 = fmaf(q1.y, w1, s1);
        s1 = fmaf(q1.z, w2, s1); s1 = fmaf(q1.w, w3, s1);
    }
    acc0 = s0; acc1 = s1;
}

// ---------------------------------------------------------------------------
// K1 (BN fused): hfn = BN_F(rawF), hbn = BN_B(rawB) computed on the fly from
// prev-step stats. Stages A1 = X + hfn into LDS (half-K tiles), computes
// x1 = sigmoid(A1 @ W1^T + b1), writes A2 = hbn + x1, A3 = x1 + hfn.
// Also zeroes the NEXT stats buffer.
// ---------------------------------------------------------------------------
__global__ __launch_bounds__(512) void k_gemm1(
    const float* __restrict__ X, const float* __restrict__ wt1,
    const float* __restrict__ b1v,
    const float* __restrict__ rawF, const float* __restrict__ rawB,
    const float* __restrict__ statPrev,
    const float* __restrict__ gF, const float* __restrict__ bF,
    const float* __restrict__ gB, const float* __restrict__ bB,
    float* __restrict__ A2, float* __restrict__ A3,
    float* __restrict__ statz, int first)
{
    __shared__ float bufA[16 * 512];          // 32KB half-K tile
    __shared__ float scF[H], ofF[H];          // 8KB F-norm tables

    int t = threadIdx.x;
    if (blockIdx.x < 8) statz[blockIdx.x * 512 + t] = 0.0f;   // 4*H floats

    int g = xcd_swizzle(blockIdx.x);
    int sb = g & 15, jb = g >> 4;
    int lane = t & 63, w = t >> 6;
    int j = (jb << 6) + lane;
    int row0 = (sb << 4) + (w << 1);
    const float inv = 1.0f / (float)S;

    if (!first) {
        for (int k = t; k < H; k += 512) {
            float m = statPrev[k] * inv;
            float v = statPrev[H + k] * inv - m * m;
            float sc = rsqrtf(v + EPS) * gF[k];
            scF[k] = sc;
            ofF[k] = bF[k] - m * sc;
        }
    }
    __syncthreads();

    float acc0 = 0.f, acc1 = 0.f;
    const float* wp = wt1 + j;
    float bias = b1v[j];

    for (int half = 0; half < 2; ++half) {
        int kbase = half << 9;
        // stage A1 tile [16][512]; 512 threads x 4 float4
#pragma unroll
        for (int it = 0; it < 4; ++it) {
            int idx4 = ((it << 9) + t) << 2;       // float index in tile
            int r = idx4 >> 9;
            int kk = idx4 & 511;
            int kg = kbase + kk;
            float4 xv = *(const float4*)(X + (sb * 16 + r) * H + kg);
            if (!first) {
                float4 rv = *(const float4*)(rawF + (sb * 16 + r) * H + kg);
                xv.x += rv.x * scF[kg] + ofF[kg];
                xv.y += rv.y * scF[kg + 1] + ofF[kg + 1];
                xv.z += rv.z * scF[kg + 2] + ofF[kg + 2];
                xv.w += rv.w * scF[kg + 3] + ofF[kg + 3];
            }
            *(float4*)(bufA + idx4) = xv;
        }
        __syncthreads();
        gemm2x64_half(bufA + (w * 2) * 512, wp + kbase * H, acc0, acc1);
        if (half == 0) __syncthreads();   // bufA reused by next half's staging
    }

    // epilogue: B-norm scale/offset for column j (from prev stats)
    float scb = 0.f, ofb = 0.f;
    if (!first) {
        float m = statPrev[2 * H + j] * inv;
        float v = statPrev[3 * H + j] * inv - m * m;
        scb = rsqrtf(v + EPS) * gB[j];
        ofb = bB[j] - m * scb;
    }
    float accs[2] = { acc0, acc1 };
#pragma unroll
    for (int r = 0; r < 2; ++r) {
        float x1 = sigm(accs[r] + bias);
        int o = (row0 + r) * H + j;
        float hb_ = first ? 0.f : rawB[o] * scb + ofb;
        float hf_ = first ? 0.f : rawF[o] * scF[j] + ofF[j];
        A2[o] = hb_ + x1;
        A3[o] = x1 + hf_;
    }
}

// ---------------------------------------------------------------------------
// K2: hb2 = sigmoid(A2 @ W2^T + b2) -> rawB (+ B stats atomics), then
// hf2 = sigmoid(A3 @ W3^T + b3) -> rawF (+ F stats). Final step writes
// out = 0.5*(hf2 + hb2).
// ---------------------------------------------------------------------------
__global__ __launch_bounds__(512) void k_gemm23(
    const float* __restrict__ A2g, const float* __restrict__ A3g,
    const float* __restrict__ wt2, const float* __restrict__ wt3,
    const float* __restrict__ b2v, const float* __restrict__ b3v,
    float* __restrict__ rawF, float* __restrict__ rawB,
    float* __restrict__ stats, float* __restrict__ outp, int writeOut)
{
    __shared__ float bufA[16 * 512];          // 32KB
    __shared__ float red[8][64][2];           // 4KB

    int t = threadIdx.x;
    int g = xcd_swizzle(blockIdx.x);
    int sb = g & 15, jb = g >> 4;
    int lane = t & 63, w = t >> 6;
    int j = (jb << 6) + lane;
    int row0 = (sb << 4) + (w << 1);

    float vb0 = 0.f, vb1 = 0.f;

    // ---------------- GEMM2: hb2 ----------------
    {
        float acc0 = 0.f, acc1 = 0.f;
        const float* wp = wt2 + j;
        for (int half = 0; half < 2; ++half) {
            int kbase = half << 9;
#pragma unroll
            for (int it = 0; it < 4; ++it) {
                int idx4 = ((it << 9) + t) << 2;
                int r = idx4 >> 9;
                int kk = idx4 & 511;
                float4 v = *(const float4*)(A2g + (sb * 16 + r) * H + kbase + kk);
                *(float4*)(bufA + idx4) = v;
            }
            __syncthreads();
            gemm2x64_half(bufA + (w * 2) * 512, wp + kbase * H, acc0, acc1);
            __syncthreads();   // bufA reused (next half or GEMM3 staging)
        }
        float bias = b2v[j];
        vb0 = sigm(acc0 + bias);
        vb1 = sigm(acc1 + bias);
        rawB[(row0 + 0) * H + j] = vb0;
        rawB[(row0 + 1) * H + j] = vb1;
        red[w][lane][0] = vb0 + vb1;
        red[w][lane][1] = vb0 * vb0 + vb1 * vb1;
    }
    __syncthreads();
    if (w == 0) {
        float ts = 0.f, tq = 0.f;
#pragma unroll
        for (int w2 = 0; w2 < 8; ++w2) { ts += red[w2][lane][0]; tq += red[w2][lane][1]; }
        atomicAdd(&stats[2 * H + j], ts);
        atomicAdd(&stats[3 * H + j], tq);
    }

    // ---------------- GEMM3: hf2 ----------------
    {
        float acc0 = 0.f, acc1 = 0.f;
        const float* wp = wt3 + j;
        for (int half = 0; half < 2; ++half) {
            int kbase = half << 9;
#pragma unroll
            for (int it = 0; it < 4; ++it) {
                int idx4 = ((it << 9) + t) << 2;
                int r = idx4 >> 9;
                int kk = idx4 & 511;
                float4 v = *(const float4*)(A3g + (sb * 16 + r) * H + kbase + kk);
                *(float4*)(bufA + idx4) = v;
            }
            __syncthreads();
            gemm2x64_half(bufA + (w * 2) * 512, wp + kbase * H, acc0, acc1);
            if (half == 0) __syncthreads();
        }
        float bias = b3v[j];
        float v0 = sigm(acc0 + bias);
        float v1 = sigm(acc1 + bias);
        rawF[(row0 + 0) * H + j] = v0;
        rawF[(row0 + 1) * H + j] = v1;
        if (writeOut) {
            outp[(row0 + 0) * H + j] = 0.5f * (v0 + vb0);
            outp[(row0 + 1) * H + j] = 0.5f * (v1 + vb1);
        }
        red[w][lane][0] = v0 + v1;
        red[w][lane][1] = v0 * v0 + v1 * v1;
    }
    __syncthreads();
    if (w == 0) {
        float ts = 0.f, tq = 0.f;
#pragma unroll
        for (int w2 = 0; w2 < 8; ++w2) { ts += red[w2][lane][0]; tq += red[w2][lane][1]; }
        atomicAdd(&stats[0 * H + j], ts);
        atomicAdd(&stats[1 * H + j], tq);
    }
}

// ---------------------------------------------------------------------------
// Host: 3 transposes + 2 kernels/step = 515 launches in one graph.
// Dead in reference: LSTM cells (discarded carry), W4/b4 (x0 dropped),
// all outs but the last. k_norm fused into k_gemm1 (BN from stats tables).
// ---------------------------------------------------------------------------
extern "C" void kernel_launch(void* const* d_in, const int* in_sizes, int n_in,
                              void* d_out, int out_size, void* d_ws, size_t ws_size,
                              hipStream_t stream) {
    (void)in_sizes; (void)n_in; (void)out_size; (void)ws_size;

    const float* X  = (const float*)d_in[0];
    const float* W1 = (const float*)d_in[1];
    const float* b1 = (const float*)d_in[2];
    const float* W2 = (const float*)d_in[3];
    const float* b2 = (const float*)d_in[4];
    const float* W3 = (const float*)d_in[5];
    const float* b3 = (const float*)d_in[6];
    const float* gf = (const float*)d_in[17];
    const float* bf = (const float*)d_in[18];
    const float* gb = (const float*)d_in[19];
    const float* bb = (const float*)d_in[20];

    float* ws    = (float*)d_ws;
    float* wt1   = ws;                  // H*H each
    float* wt2   = wt1 + H * H;
    float* wt3   = wt2 + H * H;
    float* A2    = wt3 + H * H;         // S*H
    float* A3    = A2 + SH;             // S*H
    float* rawf  = A3 + SH;             // 2 x S*H (parity)
    float* rawb  = rawf + 2 * SH;       // 2 x S*H
    float* stats = rawb + 2 * SH;       // 2 x 4*H

    k_transpose<<<1024, 256, 0, stream>>>(W1, wt1);
    k_transpose<<<1024, 256, 0, stream>>>(W2, wt2);
    k_transpose<<<1024, 256, 0, stream>>>(W3, wt3);

    for (int s = 0; s < S; ++s) {
        int p = (s + 1) & 1;           // this step's write parity
        int q = s & 1;                 // previous step's parity
        k_gemm1<<<256, 512, 0, stream>>>(
            X, wt1, b1,
            rawf + q * SH, rawb + q * SH, stats + q * 4 * H,
            gf, bf, gb, bb,
            A2, A3, stats + p * 4 * H, (s == 0) ? 1 : 0);
        k_gemm23<<<256, 512, 0, stream>>>(
            A2, A3, wt2, wt3, b2, b3,
            rawf + p * SH, rawb + p * SH, stats + p * 4 * H,
            (float*)d_out, (s == S - 1) ? 1 : 0);
    }
}

// Round 3
// 14970.891 us; speedup vs baseline: 2.5801x; 1.5550x over previous
//
#include <hip/hip_runtime.h>
#include <hip/hip_bf16.h>
#include <math.h>

#define S 256
#define H 1024
#define SH (S*H)
#define EPS 1e-5f

typedef float f32x4 __attribute__((ext_vector_type(4)));
typedef short bf16x8 __attribute__((ext_vector_type(8)));   // 8 bf16 in 4 VGPRs

__device__ __forceinline__ float sigm(float x){ return 1.0f/(1.0f+expf(-x)); }

__device__ __forceinline__ ushort f2bf(float a){
    union { __hip_bfloat16 b; ushort u; } cv;
    cv.b = __float2bfloat16(a);
    return cv.u;
}
__device__ __forceinline__ float bf2f(ushort u){
    union { __hip_bfloat16 b; ushort u; } cv; cv.u = u;
    return __bfloat162float(cv.b);
}

// bijective for 256 blocks; decode sb=g&7 (row grp), jb=g>>3 (col grp):
// XCD x gets g in [32x,32x+32) -> 4 contiguous 32-col W slabs (1.5MB, L2-resident)
__device__ __forceinline__ int xcd_swizzle(unsigned gbx) {
    return (int)((gbx & 7u) * 32u + (gbx >> 3));
}

// ---------------------------------------------------------------------------
// Pack W[j][k] (fp32 HxH) into MFMA B-fragment layout, bf16 hi/lo split:
// Wp[jt][ktg][lane][e] = W[jt*16+(lane&15)][ktg*32+(lane>>4)*8+e]
// jt in [0,64), ktg in [0,32): 1M bf16 = 2MB each.
// ---------------------------------------------------------------------------
__global__ __launch_bounds__(256) void k_pack(const float* __restrict__ W,
                                              ushort* __restrict__ ph,
                                              ushort* __restrict__ pl) {
    int p  = blockIdx.x * 256 + threadIdx.x;   // 131072 (jt,ktg,lane) slots
    int l  = p & 63;
    int kt = (p >> 6) & 31;
    int jt = p >> 11;
    int j  = jt * 16 + (l & 15);
    int k0 = kt * 32 + ((l >> 4) << 3);
    const float* src = W + j * H + k0;
    float4 a0 = *(const float4*)src;
    float4 a1 = *(const float4*)(src + 4);
    float av[8] = {a0.x,a0.y,a0.z,a0.w,a1.x,a1.y,a1.z,a1.w};
    bf16x8 vh, vl;
#pragma unroll
    for (int e = 0; e < 8; ++e) {
        ushort h = f2bf(av[e]);
        vh[e] = (short)h;
        vl[e] = (short)f2bf(av[e] - bf2f(h));
    }
    *(bf16x8*)(ph + (size_t)p * 8) = vh;
    *(bf16x8*)(pl + (size_t)p * 8) = vl;
}

// ---------------------------------------------------------------------------
// K1: BN(prev) fused; x1 = sigmoid((X+hf) @ W1^T + b1) via bf16x3 MFMA.
// Writes A2 = hb + x1, A3 = x1 + hf. Zeroes next-step stats.
// Block: 32 rows x 32 cols, 4 waves (2x2), wave = one 16x16 tile, K staged
// in 256-wide quarters in LDS (frag layout, lane-contiguous ds_read_b128).
// ---------------------------------------------------------------------------
__global__ __launch_bounds__(256) void k_gemm1(
    const float* __restrict__ X,
    const ushort* __restrict__ Wph, const ushort* __restrict__ Wpl,
    const float* __restrict__ b1v,
    const float* __restrict__ rawF, const float* __restrict__ rawB,
    const float* __restrict__ statPrev,
    const float* __restrict__ gF, const float* __restrict__ bF,
    const float* __restrict__ gB, const float* __restrict__ bB,
    float* __restrict__ A2, float* __restrict__ A3,
    float* __restrict__ statz, int first)
{
    __shared__ __align__(16) ushort lhs_hi[8192];   // [st2][kc][64][8] bf16
    __shared__ __align__(16) ushort lhs_lo[8192];
    __shared__ float scF[H], ofF[H];

    int t = threadIdx.x;
    if (blockIdx.x < 16) statz[blockIdx.x * 256 + t] = 0.0f;   // 4*H floats

    int g = xcd_swizzle(blockIdx.x);
    int sb = g & 7, jb = g >> 3;
    int lane = t & 63, w = t >> 6;
    int wr = w >> 1, wc = w & 1;
    int row0 = sb * 32;
    int jt = jb * 2 + wc;
    const float inv = 1.0f / (float)S;

    if (!first) {
        for (int k = t; k < H; k += 256) {
            float m = statPrev[k] * inv;
            float v = statPrev[H + k] * inv - m * m;
            float sc = rsqrtf(v + EPS) * gF[k];
            scF[k] = sc;
            ofF[k] = bF[k] - m * sc;
        }
    }
    __syncthreads();

    f32x4 acc0 = {0,0,0,0}, acc1 = {0,0,0,0}, acc2 = {0,0,0,0};

    for (int phase = 0; phase < 4; ++phase) {
        int kbase = phase << 8;
#pragma unroll
        for (int it = 0; it < 4; ++it) {
            int gg = t + (it << 8);          // 0..1023: 32 rows x 32 k-groups
            int s  = gg & 31;
            int kg = gg >> 5;
            int k  = kbase + (kg << 3);
            const float* xp = X + (row0 + s) * H + k;
            float4 x0 = *(const float4*)xp;
            float4 x1 = *(const float4*)(xp + 4);
            float a[8] = {x0.x,x0.y,x0.z,x0.w,x1.x,x1.y,x1.z,x1.w};
            if (!first) {
                const float* rp = rawF + (row0 + s) * H + k;
                float4 r0 = *(const float4*)rp;
                float4 r1 = *(const float4*)(rp + 4);
                float rr[8] = {r0.x,r0.y,r0.z,r0.w,r1.x,r1.y,r1.z,r1.w};
#pragma unroll
                for (int e = 0; e < 8; ++e)
                    a[e] += rr[e] * scF[k + e] + ofF[k + e];
            }
            bf16x8 vh, vl;
#pragma unroll
            for (int e = 0; e < 8; ++e) {
                ushort h = f2bf(a[e]);
                vh[e] = (short)h;
                vl[e] = (short)f2bf(a[e] - bf2f(h));
            }
            int st2 = s >> 4, q = kg & 3, kc = kg >> 2;
            int idx = (((st2 * 8 + kc) * 64) + ((q << 4) | (s & 15))) * 8;
            *(bf16x8*)(lhs_hi + idx) = vh;
            *(bf16x8*)(lhs_lo + idx) = vl;
        }
        __syncthreads();
        const ushort* bph = Wph + ((size_t)(jt * 32 + (phase << 3)) * 64 + lane) * 8;
        const ushort* bpl = Wpl + ((size_t)(jt * 32 + (phase << 3)) * 64 + lane) * 8;
        const ushort* ah  = lhs_hi + ((wr * 8) * 64 + lane) * 8;
        const ushort* al  = lhs_lo + ((wr * 8) * 64 + lane) * 8;
#pragma unroll
        for (int kc = 0; kc < 8; ++kc) {
            bf16x8 a_h = *(const bf16x8*)(ah + kc * 512);
            bf16x8 a_l = *(const bf16x8*)(al + kc * 512);
            bf16x8 b_h = *(const bf16x8*)(bph + kc * 512);
            bf16x8 b_l = *(const bf16x8*)(bpl + kc * 512);
            acc0 = __builtin_amdgcn_mfma_f32_16x16x32_bf16(a_h, b_h, acc0, 0, 0, 0);
            acc1 = __builtin_amdgcn_mfma_f32_16x16x32_bf16(a_h, b_l, acc1, 0, 0, 0);
            acc2 = __builtin_amdgcn_mfma_f32_16x16x32_bf16(a_l, b_h, acc2, 0, 0, 0);
        }
        __syncthreads();
    }

    int j = jt * 16 + (lane & 15);
    int srow = row0 + wr * 16 + ((lane >> 4) << 2);
    float bias = b1v[j];
    float scFj = 0.f, ofFj = 0.f, scBj = 0.f, ofBj = 0.f;
    if (!first) {
        scFj = scF[j]; ofFj = ofF[j];
        float m = statPrev[2 * H + j] * inv;
        float v = statPrev[3 * H + j] * inv - m * m;
        scBj = rsqrtf(v + EPS) * gB[j];
        ofBj = bB[j] - m * scBj;
    }
    f32x4 sum = acc0 + acc1 + acc2;
#pragma unroll
    for (int r = 0; r < 4; ++r) {
        int o = (srow + r) * H + j;
        float x1v = sigm(sum[r] + bias);
        float hb_ = first ? 0.f : rawB[o] * scBj + ofBj;
        float hf_ = first ? 0.f : rawF[o] * scFj + ofFj;
        A2[o] = hb_ + x1v;
        A3[o] = x1v + hf_;
    }
}

// ---------------------------------------------------------------------------
// K2: hb2 = sig(A2@W2^T+b2) -> rawB (+stats), hf2 = sig(A3@W3^T+b3) -> rawF
// (+stats); final step writes out = 0.5*(hf2+hb2). Same MFMA structure.
// ---------------------------------------------------------------------------
__global__ __launch_bounds__(256) void k_gemm23(
    const float* __restrict__ A2g, const float* __restrict__ A3g,
    const ushort* __restrict__ W2h, const ushort* __restrict__ W2l,
    const ushort* __restrict__ W3h, const ushort* __restrict__ W3l,
    const float* __restrict__ b2v, const float* __restrict__ b3v,
    float* __restrict__ rawF, float* __restrict__ rawB,
    float* __restrict__ stats, float* __restrict__ outp, int writeOut)
{
    __shared__ __align__(16) ushort lhs_hi[8192];
    __shared__ __align__(16) ushort lhs_lo[8192];
    __shared__ float red[4][64][2];

    int t = threadIdx.x;
    int g = xcd_swizzle(blockIdx.x);
    int sb = g & 7, jb = g >> 3;
    int lane = t & 63, w = t >> 6;
    int wr = w >> 1, wc = w & 1;
    int row0 = sb * 32;
    int jt = jb * 2 + wc;
    int j = jt * 16 + (lane & 15);
    int srow = row0 + wr * 16 + ((lane >> 4) << 2);

    float vb[4];

    // ================= GEMM2: A2 @ W2 =================
    {
        f32x4 acc0 = {0,0,0,0}, acc1 = {0,0,0,0}, acc2 = {0,0,0,0};
        for (int phase = 0; phase < 4; ++phase) {
            int kbase = phase << 8;
#pragma unroll
            for (int it = 0; it < 4; ++it) {
                int gg = t + (it << 8);
                int s = gg & 31, kg = gg >> 5;
                int k = kbase + (kg << 3);
                const float* xp = A2g + (row0 + s) * H + k;
                float4 x0 = *(const float4*)xp;
                float4 x1 = *(const float4*)(xp + 4);
                float a[8] = {x0.x,x0.y,x0.z,x0.w,x1.x,x1.y,x1.z,x1.w};
                bf16x8 vh, vl;
#pragma unroll
                for (int e = 0; e < 8; ++e) {
                    ushort h = f2bf(a[e]);
                    vh[e] = (short)h;
                    vl[e] = (short)f2bf(a[e] - bf2f(h));
                }
                int idx = ((((s >> 4) * 8 + (kg >> 2)) * 64) + (((kg & 3) << 4) | (s & 15))) * 8;
                *(bf16x8*)(lhs_hi + idx) = vh;
                *(bf16x8*)(lhs_lo + idx) = vl;
            }
            __syncthreads();
            const ushort* bph = W2h + ((size_t)(jt * 32 + (phase << 3)) * 64 + lane) * 8;
            const ushort* bpl = W2l + ((size_t)(jt * 32 + (phase << 3)) * 64 + lane) * 8;
            const ushort* ah  = lhs_hi + ((wr * 8) * 64 + lane) * 8;
            const ushort* al  = lhs_lo + ((wr * 8) * 64 + lane) * 8;
#pragma unroll
            for (int kc = 0; kc < 8; ++kc) {
                bf16x8 a_h = *(const bf16x8*)(ah + kc * 512);
                bf16x8 a_l = *(const bf16x8*)(al + kc * 512);
                bf16x8 b_h = *(const bf16x8*)(bph + kc * 512);
                bf16x8 b_l = *(const bf16x8*)(bpl + kc * 512);
                acc0 = __builtin_amdgcn_mfma_f32_16x16x32_bf16(a_h, b_h, acc0, 0, 0, 0);
                acc1 = __builtin_amdgcn_mfma_f32_16x16x32_bf16(a_h, b_l, acc1, 0, 0, 0);
                acc2 = __builtin_amdgcn_mfma_f32_16x16x32_bf16(a_l, b_h, acc2, 0, 0, 0);
            }
            __syncthreads();
        }
        f32x4 sum = acc0 + acc1 + acc2;
        float bias = b2v[j];
        float ts = 0.f, tq = 0.f;
#pragma unroll
        for (int r = 0; r < 4; ++r) {
            float v = sigm(sum[r] + bias);
            vb[r] = v;
            rawB[(srow + r) * H + j] = v;
            ts += v; tq += v * v;
        }
        red[w][lane][0] = ts;
        red[w][lane][1] = tq;
    }
    __syncthreads();
    if (t < 32) {
        int wc2 = t >> 4, jl = t & 15;
        int jj = jb * 32 + wc2 * 16 + jl;
        float ts = 0.f, tq = 0.f;
#pragma unroll
        for (int wr2 = 0; wr2 < 2; ++wr2)
#pragma unroll
            for (int lg = 0; lg < 4; ++lg) {
                ts += red[wr2 * 2 + wc2][lg * 16 + jl][0];
                tq += red[wr2 * 2 + wc2][lg * 16 + jl][1];
            }
        atomicAdd(&stats[2 * H + jj], ts);
        atomicAdd(&stats[3 * H + jj], tq);
    }

    // ================= GEMM3: A3 @ W3 =================
    {
        f32x4 acc0 = {0,0,0,0}, acc1 = {0,0,0,0}, acc2 = {0,0,0,0};
        for (int phase = 0; phase < 4; ++phase) {
            int kbase = phase << 8;
            __syncthreads();   // ensure stats-reduce read of red[] done / prev mfma reads done
#pragma unroll
            for (int it = 0; it < 4; ++it) {
                int gg = t + (it << 8);
                int s = gg & 31, kg = gg >> 5;
                int k = kbase + (kg << 3);
                const float* xp = A3g + (row0 + s) * H + k;
                float4 x0 = *(const float4*)xp;
                float4 x1 = *(const float4*)(xp + 4);
                float a[8] = {x0.x,x0.y,x0.z,x0.w,x1.x,x1.y,x1.z,x1.w};
                bf16x8 vh, vl;
#pragma unroll
                for (int e = 0; e < 8; ++e) {
                    ushort h = f2bf(a[e]);
                    vh[e] = (short)h;
                    vl[e] = (short)f2bf(a[e] - bf2f(h));
                }
                int idx = ((((s >> 4) * 8 + (kg >> 2)) * 64) + (((kg & 3) << 4) | (s & 15))) * 8;
                *(bf16x8*)(lhs_hi + idx) = vh;
                *(bf16x8*)(lhs_lo + idx) = vl;
            }
            __syncthreads();
            const ushort* bph = W3h + ((size_t)(jt * 32 + (phase << 3)) * 64 + lane) * 8;
            const ushort* bpl = W3l + ((size_t)(jt * 32 + (phase << 3)) * 64 + lane) * 8;
            const ushort* ah  = lhs_hi + ((wr * 8) * 64 + lane) * 8;
            const ushort* al  = lhs_lo + ((wr * 8) * 64 + lane) * 8;
#pragma unroll
            for (int kc = 0; kc < 8; ++kc) {
                bf16x8 a_h = *(const bf16x8*)(ah + kc * 512);
                bf16x8 a_l = *(const bf16x8*)(al + kc * 512);
                bf16x8 b_h = *(const bf16x8*)(bph + kc * 512);
                bf16x8 b_l = *(const bf16x8*)(bpl + kc * 512);
                acc0 = __builtin_amdgcn_mfma_f32_16x16x32_bf16(a_h, b_h, acc0, 0, 0, 0);
                acc1 = __builtin_amdgcn_mfma_f32_16x16x32_bf16(a_h, b_l, acc1, 0, 0, 0);
                acc2 = __builtin_amdgcn_mfma_f32_16x16x32_bf16(a_l, b_h, acc2, 0, 0, 0);
            }
        }
        __syncthreads();
        f32x4 sum = acc0 + acc1 + acc2;
        float bias = b3v[j];
        float ts = 0.f, tq = 0.f;
#pragma unroll
        for (int r = 0; r < 4; ++r) {
            float v = sigm(sum[r] + bias);
            rawF[(srow + r) * H + j] = v;
            if (writeOut)
                outp[(srow + r) * H + j] = 0.5f * (v + vb[r]);
            ts += v; tq += v * v;
        }
        red[w][lane][0] = ts;
        red[w][lane][1] = tq;
    }
    __syncthreads();
    if (t < 32) {
        int wc2 = t >> 4, jl = t & 15;
        int jj = jb * 32 + wc2 * 16 + jl;
        float ts = 0.f, tq = 0.f;
#pragma unroll
        for (int wr2 = 0; wr2 < 2; ++wr2)
#pragma unroll
            for (int lg = 0; lg < 4; ++lg) {
                ts += red[wr2 * 2 + wc2][lg * 16 + jl][0];
                tq += red[wr2 * 2 + wc2][lg * 16 + jl][1];
            }
        atomicAdd(&stats[0 * H + jj], ts);
        atomicAdd(&stats[1 * H + jj], tq);
    }
}

// ---------------------------------------------------------------------------
// Host. Dead in reference: LSTM cells (discarded carry), W4/b4, all outs but
// last. 3 pack + 512 step kernels in one graph.
// ---------------------------------------------------------------------------
extern "C" void kernel_launch(void* const* d_in, const int* in_sizes, int n_in,
                              void* d_out, int out_size, void* d_ws, size_t ws_size,
                              hipStream_t stream) {
    (void)in_sizes; (void)n_in; (void)out_size; (void)ws_size;

    const float* X  = (const float*)d_in[0];
    const float* W1 = (const float*)d_in[1];
    const float* b1 = (const float*)d_in[2];
    const float* W2 = (const float*)d_in[3];
    const float* b2 = (const float*)d_in[4];
    const float* W3 = (const float*)d_in[5];
    const float* b3 = (const float*)d_in[6];
    const float* gf = (const float*)d_in[17];
    const float* bf = (const float*)d_in[18];
    const float* gb = (const float*)d_in[19];
    const float* bb = (const float*)d_in[20];

    char* base = (char*)d_ws;
    const size_t MB = 1024 * 1024;
    ushort* wp1h = (ushort*)(base + 0 * MB);
    ushort* wp1l = (ushort*)(base + 2 * MB);
    ushort* wp2h = (ushort*)(base + 4 * MB);
    ushort* wp2l = (ushort*)(base + 6 * MB);
    ushort* wp3h = (ushort*)(base + 8 * MB);
    ushort* wp3l = (ushort*)(base + 10 * MB);
    float*  A2   = (float*)(base + 12 * MB);
    float*  A3   = (float*)(base + 13 * MB);
    float*  rawf = (float*)(base + 14 * MB);   // 2 parities
    float*  rawb = (float*)(base + 16 * MB);   // 2 parities
    float*  stats= (float*)(base + 18 * MB);   // 2 parities x 4H

    k_pack<<<512, 256, 0, stream>>>(W1, wp1h, wp1l);
    k_pack<<<512, 256, 0, stream>>>(W2, wp2h, wp2l);
    k_pack<<<512, 256, 0, stream>>>(W3, wp3h, wp3l);

    for (int s = 0; s < S; ++s) {
        int p = (s + 1) & 1;
        int q = s & 1;
        k_gemm1<<<256, 256, 0, stream>>>(
            X, wp1h, wp1l, b1,
            rawf + q * SH, rawb + q * SH, stats + q * 4 * H,
            gf, bf, gb, bb,
            A2, A3, stats + p * 4 * H, (s == 0) ? 1 : 0);
        k_gemm23<<<256, 256, 0, stream>>>(
            A2, A3, wp2h, wp2l, wp3h, wp3l, b2, b3,
            rawf + p * SH, rawb + p * SH, stats + p * 4 * H,
            (float*)d_out, (s == S - 1) ? 1 : 0);
    }
}